// Round 1
// 625.582 us; speedup vs baseline: 1.1130x; 1.1130x over previous
//
#include <hip/hip_runtime.h>
#include <stdint.h>

#define Lc 96
#define Hc 8
#define Ec 64
#define EHc 128
#define APu 72           // A plane pitch in ushorts (144 B rows, 16B-aligned)
#define HPu 136          // H plane pitch in ushorts (272 B rows, 16B-aligned)
#define JS (Hc * Ec * 2) // out stride per j = 1024 floats

typedef __attribute__((ext_vector_type(8))) short short8;
typedef __attribute__((ext_vector_type(4))) float floatx4;

union FragH { uint16_t h[8]; short8 v; };

// tanh(x) = 1 - 2/(e^{2x}+1)
__device__ __forceinline__ float fast_tanh(float x) {
    const float e = __builtin_amdgcn_exp2f(x * 2.8853900817779268f);
    return 1.0f - 2.0f * __builtin_amdgcn_rcpf(e + 1.0f);
}

// barrier that drains LDS only — does NOT wait for in-flight global stores
// (out regions are disjoint and never read back, so vmcnt drain is wasted time)
__device__ __forceinline__ void lds_barrier() {
    asm volatile("s_waitcnt lgkmcnt(0)\n\ts_barrier" ::: "memory");
}

// Block = 4 waves x 64 = 256 threads; M = 16 rows (one trajectory slice).
// Wave w owns: L1 hidden cols [32w,32w+32) (2 col-tiles), L2 out cols [16w,16w+16).
// Weights are register-resident B-frags (bf16 hi/lo). Activations round-trip LDS
// as PLANAR bf16 hi/lo arrays: producers ds_write_b16 each half, consumers get
// MFMA A-frags directly via ds_read_b128 — zero bit-repack VALU on the read side.
__global__ __launch_bounds__(256, 2)
void ode_mfma_kernel(const float* __restrict__ x, const float* __restrict__ ts,
                     const float* __restrict__ W1, const float* __restrict__ b1,
                     const float* __restrict__ W2, const float* __restrict__ b2,
                     float* __restrict__ out)
{
    __shared__ alignas(16) uint16_t A_hi[16 * APu];   // arg hi-bf16, [row][e]
    __shared__ alignas(16) uint16_t A_lo[16 * APu];   // arg lo-bf16
    __shared__ alignas(16) uint16_t H_hi[16 * HPu];   // hidden hi-bf16, [row][n]
    __shared__ alignas(16) uint16_t H_lo[16 * HPu];   // hidden lo-bf16
    __shared__ float tss[Lc];

    const int tid  = threadIdx.x;
    const int w    = tid >> 6;      // wave 0..3
    const int lane = tid & 63;
    const int g    = lane >> 4;     // quad 0..3
    const int c    = lane & 15;

    if (tid < Lc) tss[tid] = ts[tid];

    // ---- register-resident weight B-fragments: B[k = ks*32 + g*8 + j][n] ----
    short8 w1h[2][2], w1l[2][2];           // [ct][ks]
#pragma unroll
    for (int ct = 0; ct < 2; ++ct)
#pragma unroll
        for (int ks = 0; ks < 2; ++ks) {
            FragH fh, fl;
#pragma unroll
            for (int j = 0; j < 8; ++j) {
                const int k = ks * 32 + g * 8 + j;
                const int n = 32 * w + 16 * ct + c;
                const float v = W1[k * EHc + n];
                const uint32_t uv = __float_as_uint(v);
                const float hf = __uint_as_float(uv & 0xffff0000u);
                fh.h[j] = (uint16_t)(uv >> 16);
                fl.h[j] = (uint16_t)(__float_as_uint(v - hf) >> 16);
            }
            w1h[ct][ks] = fh.v; w1l[ct][ks] = fl.v;
        }
    short8 w2h[4], w2l[4];                 // [ks]
#pragma unroll
    for (int ks = 0; ks < 4; ++ks) {
        FragH fh, fl;
#pragma unroll
        for (int j = 0; j < 8; ++j) {
            const int k = ks * 32 + g * 8 + j;
            const int n = 16 * w + c;
            const float v = W2[k * Ec + n];
            const uint32_t uv = __float_as_uint(v);
            const float hf = __uint_as_float(uv & 0xffff0000u);
            fh.h[j] = (uint16_t)(uv >> 16);
            fl.h[j] = (uint16_t)(__float_as_uint(v - hf) >> 16);
        }
        w2h[ks] = fh.v; w2l[ks] = fl.v;
    }

    const float b1v0 = b1[32 * w + c];
    const float b1v1 = b1[32 * w + 16 + c];
    const float b2v  = b2[16 * w + c];

    // ---- per-lane state: C/D layout, rows r = g*4+reg, col e = 16w+c ----
    const int t_blk = (blockIdx.x * 16) >> 6;    // uniform: 16 divides 64
    const int fs    = (Lc - 1) - t_blk;          // forward step count
    const int col   = 16 * w + c;

    float y0_[4], y_[4];
    float* outp[4];
#pragma unroll
    for (int reg = 0; reg < 4; ++reg) {
        const int rs = blockIdx.x * 16 + g * 4 + reg;   // global row-slot
        const int bidx = (rs & 63) >> 3;
        const int hh   = rs & 7;
        const float v0 = x[((bidx * Lc + t_blk) * Hc + hh) * Ec + col];
        y0_[reg] = v0; y_[reg] = v0;
        outp[reg] = out + (size_t)(bidx * Lc + t_blk) * (Lc * JS) + hh * (Ec * 2) + col * 2;
        float2 o; o.x = v0; o.y = v0;                   // j = t: (y0, y0)
        *(float2*)(outp[reg] + (size_t)t_blk * JS) = o;
        const int r = g * 4 + reg;
        const uint32_t uv = __float_as_uint(v0);
        A_hi[r * APu + col] = (uint16_t)(uv >> 16);
        A_lo[r * APu + col] =
            (uint16_t)(__float_as_uint(v0 - __uint_as_float(uv & 0xffff0000u)) >> 16);
    }
    __syncthreads();

    const int arow = c * APu + g * 8;    // A-frag base (u16 units), 16B-aligned
    const int hrow = c * HPu + g * 8;    // H-frag base
    const int hcol = 32 * w + c;

    // f(A planes) -> this lane's 4 output values (C/D layout). Entry: A synced.
    // One internal barrier (H handoff). Caller barriers after next A write.
    auto evalf = [&]() -> floatx4 {
        const short8 a0h = *(const short8*)(A_hi + arow);
        const short8 a1h = *(const short8*)(A_hi + arow + 32);
        const short8 a0l = *(const short8*)(A_lo + arow);
        const short8 a1l = *(const short8*)(A_lo + arow + 32);

        floatx4 p0 = {b1v0, b1v0, b1v0, b1v0};
        floatx4 p1 = {b1v1, b1v1, b1v1, b1v1};
        p0 = __builtin_amdgcn_mfma_f32_16x16x32_bf16(a0h, w1h[0][0], p0, 0, 0, 0);
        p0 = __builtin_amdgcn_mfma_f32_16x16x32_bf16(a0h, w1l[0][0], p0, 0, 0, 0);
        p0 = __builtin_amdgcn_mfma_f32_16x16x32_bf16(a0l, w1h[0][0], p0, 0, 0, 0);
        p1 = __builtin_amdgcn_mfma_f32_16x16x32_bf16(a0h, w1h[1][0], p1, 0, 0, 0);
        p1 = __builtin_amdgcn_mfma_f32_16x16x32_bf16(a0h, w1l[1][0], p1, 0, 0, 0);
        p1 = __builtin_amdgcn_mfma_f32_16x16x32_bf16(a0l, w1h[1][0], p1, 0, 0, 0);
        p0 = __builtin_amdgcn_mfma_f32_16x16x32_bf16(a1h, w1h[0][1], p0, 0, 0, 0);
        p0 = __builtin_amdgcn_mfma_f32_16x16x32_bf16(a1h, w1l[0][1], p0, 0, 0, 0);
        p0 = __builtin_amdgcn_mfma_f32_16x16x32_bf16(a1l, w1h[0][1], p0, 0, 0, 0);
        p1 = __builtin_amdgcn_mfma_f32_16x16x32_bf16(a1h, w1h[1][1], p1, 0, 0, 0);
        p1 = __builtin_amdgcn_mfma_f32_16x16x32_bf16(a1h, w1l[1][1], p1, 0, 0, 0);
        p1 = __builtin_amdgcn_mfma_f32_16x16x32_bf16(a1l, w1h[1][1], p1, 0, 0, 0);

#pragma unroll
        for (int reg = 0; reg < 4; ++reg) {
            const int r = g * 4 + reg;
            const float t0 = fast_tanh(p0[reg]);
            const float t1 = fast_tanh(p1[reg]);
            const uint32_t u0 = __float_as_uint(t0);
            const uint32_t u1 = __float_as_uint(t1);
            H_hi[r * HPu + hcol]      = (uint16_t)(u0 >> 16);
            H_lo[r * HPu + hcol]      =
                (uint16_t)(__float_as_uint(t0 - __uint_as_float(u0 & 0xffff0000u)) >> 16);
            H_hi[r * HPu + hcol + 16] = (uint16_t)(u1 >> 16);
            H_lo[r * HPu + hcol + 16] =
                (uint16_t)(__float_as_uint(t1 - __uint_as_float(u1 & 0xffff0000u)) >> 16);
        }
        lds_barrier();

        floatx4 o = {b2v, b2v, b2v, b2v};
#pragma unroll
        for (int ks = 0; ks < 4; ++ks) {
            const short8 hh_ = *(const short8*)(H_hi + hrow + ks * 32);
            const short8 hl_ = *(const short8*)(H_lo + hrow + ks * 32);
            o = __builtin_amdgcn_mfma_f32_16x16x32_bf16(hh_, w2h[ks], o, 0, 0, 0);
            o = __builtin_amdgcn_mfma_f32_16x16x32_bf16(hh_, w2l[ks], o, 0, 0, 0);
            o = __builtin_amdgcn_mfma_f32_16x16x32_bf16(hl_, w2h[ks], o, 0, 0, 0);
        }
        return o;
    };

    auto putA = [&](const float* a4) {
#pragma unroll
        for (int reg = 0; reg < 4; ++reg) {
            const int r = g * 4 + reg;
            const float v = a4[reg];
            const uint32_t uv = __float_as_uint(v);
            A_hi[r * APu + col] = (uint16_t)(uv >> 16);
            A_lo[r * APu + col] =
                (uint16_t)(__float_as_uint(v - __uint_as_float(uv & 0xffff0000u)) >> 16);
        }
        lds_barrier();
    };

    for (int v = 0; v < Lc - 1; ++v) {
        float dt; int jo;
        if (v < fs) { const int s = t_blk + v;        dt = tss[s + 1] - tss[s]; jo = s + 1; }
        else        { const int s = t_blk - (v - fs); dt = tss[s - 1] - tss[s]; jo = s - 1; }

        float a[4];
        const floatx4 k1 = evalf();
#pragma unroll
        for (int reg = 0; reg < 4; ++reg)
            a[reg] = fmaf(dt * (1.0f / 3.0f), k1[reg], y_[reg]);
        putA(a);
        const floatx4 k2 = evalf();
#pragma unroll
        for (int reg = 0; reg < 4; ++reg)
            a[reg] = y_[reg] + dt * (k2[reg] - (1.0f / 3.0f) * k1[reg]);
        putA(a);
        const floatx4 k3 = evalf();
#pragma unroll
        for (int reg = 0; reg < 4; ++reg)
            a[reg] = y_[reg] + dt * (k1[reg] - k2[reg] + k3[reg]);
        putA(a);
        const floatx4 k4 = evalf();
#pragma unroll
        for (int reg = 0; reg < 4; ++reg) {
            y_[reg] += dt * (k1[reg] + 3.0f * (k2[reg] + k3[reg]) + k4[reg]) * 0.125f;
            float2 o; o.x = y0_[reg]; o.y = y_[reg];
            *(float2*)(outp[reg] + (size_t)jo * JS) = o;
        }
        if (v + 1 == fs) {
#pragma unroll
            for (int reg = 0; reg < 4; ++reg) y_[reg] = y0_[reg];  // start bwd sweep
        }
#pragma unroll
        for (int reg = 0; reg < 4; ++reg) a[reg] = y_[reg];
        putA(a);
    }
}

extern "C" void kernel_launch(void* const* d_in, const int* in_sizes, int n_in,
                              void* d_out, int out_size, void* d_ws, size_t ws_size,
                              hipStream_t stream) {
    const float* x  = (const float*)d_in[0];
    const float* ts = (const float*)d_in[1];
    const float* W1 = (const float*)d_in[2];
    const float* b1 = (const float*)d_in[3];
    const float* W2 = (const float*)d_in[4];
    const float* b2 = (const float*)d_in[5];
    float* out = (float*)d_out;

    dim3 grid(6144 / 16);   // 384 blocks x 16 rows = 96 traj x 64 rows
    dim3 block(256);
    ode_mfma_kernel<<<grid, block, 0, stream>>>(x, ts, W1, b1, W2, b2, out);
}